// Round 2
// 856.957 us; speedup vs baseline: 1.0190x; 1.0190x over previous
//
#include <hip/hip_runtime.h>
#include <hip/hip_bf16.h>
#include <stdint.h>

// Problem constants (reference: B,S,N,H,D = 8,2048,8,1024,64, T=50)
#define BB 8
#define SS 2048
#define NTASK 8
#define HH 1024
#define DD 64
#define TEMP 50.0f

typedef __attribute__((ext_vector_type(8))) short short8;   // 8 bf16 (4 VGPRs)
typedef __attribute__((ext_vector_type(4))) float floatx4;  // 4 fp32

static __device__ __forceinline__ unsigned short f2bf(float f) {
  // round-to-nearest-even fp32 -> bf16
  union { float f; unsigned int u; } v; v.f = f;
  unsigned int u = v.u;
  unsigned int r = u + 0x7FFFu + ((u >> 16) & 1u);
  return (unsigned short)(r >> 16);
}

// ---------------------------------------------------------------------------
// Kernel 1: masked pooling sums over S. grid = BB*64 blocks (64 s-chunks of 32),
// 256 threads. Accumulate via atomicAdd into zeroed ws buffers.
// valid[s] is BLOCK-UNIFORM -> `if (valid[s])` is a free scalar branch that
// skips the HBM fetch for masked rows (~50% of query+key traffic).
// Also folds the Wv fp32->bf16 cast (512 blk * 256 thr * 8 = 1M elems).
// ---------------------------------------------------------------------------
#define SCHUNKS 64
#define SCHUNK (SS / SCHUNKS)  // 32

__global__ void pool_kernel(const float* __restrict__ query,
                            const float* __restrict__ key,
                            const int* __restrict__ amask,
                            const float* __restrict__ Wv,
                            float* __restrict__ qsum,    // [BB,HH]
                            float* __restrict__ ksum,    // [BB,NTASK*DD]
                            float* __restrict__ lensum,  // [BB]
                            unsigned short* __restrict__ WvB)
{
  __shared__ float valid[SCHUNK];
  int b = blockIdx.x >> 6;
  int chunk = blockIdx.x & 63;
  int s0 = chunk * SCHUNK;
  int tid = threadIdx.x;
  if (tid < SCHUNK) valid[tid] = (amask[b * SS + s0 + tid] == 0) ? 1.0f : 0.0f;
  __syncthreads();

  // Wv cast (independent of pooling): 8 consecutive elements per thread.
  {
    size_t i = ((size_t)blockIdx.x * 256 + tid) * 8;
    floatx4 v0 = *(const floatx4*)(Wv + i);
    floatx4 v1 = *(const floatx4*)(Wv + i + 4);
    union { unsigned short us[8]; uint4 u4; } pk;
    pk.us[0] = f2bf(v0.x); pk.us[1] = f2bf(v0.y);
    pk.us[2] = f2bf(v0.z); pk.us[3] = f2bf(v0.w);
    pk.us[4] = f2bf(v1.x); pk.us[5] = f2bf(v1.y);
    pk.us[6] = f2bf(v1.z); pk.us[7] = f2bf(v1.w);
    *(uint4*)(WvB + i) = pk.u4;
  }

  // query pooling: thread handles 4 consecutive h (float4), coalesced across lanes
  {
    const float* qb = query + ((size_t)b * SS + s0) * HH;
    int h0 = tid * 4;  // 256*4 = 1024 = HH
    floatx4 acc = {0.f, 0.f, 0.f, 0.f};
    for (int s = 0; s < SCHUNK; ++s) {
      if (valid[s] != 0.0f) {  // block-uniform branch: skip masked rows
        floatx4 v = *(const floatx4*)(qb + (size_t)s * HH + h0);
        acc += v;
      }
    }
    atomicAdd(&qsum[b * HH + h0 + 0], acc.x);
    atomicAdd(&qsum[b * HH + h0 + 1], acc.y);
    atomicAdd(&qsum[b * HH + h0 + 2], acc.z);
    atomicAdd(&qsum[b * HH + h0 + 3], acc.w);
  }
  // key pooling: NTASK*DD = 512 floats = 128 float4s; threads 0..127
  if (tid < 128) {
    const float* kb = key + ((size_t)b * SS + s0) * (NTASK * DD);
    int i0 = tid * 4;
    floatx4 acc = {0.f, 0.f, 0.f, 0.f};
    for (int s = 0; s < SCHUNK; ++s) {
      if (valid[s] != 0.0f) {
        floatx4 v = *(const floatx4*)(kb + (size_t)s * (NTASK * DD) + i0);
        acc += v;
      }
    }
    atomicAdd(&ksum[b * NTASK * DD + i0 + 0], acc.x);
    atomicAdd(&ksum[b * NTASK * DD + i0 + 1], acc.y);
    atomicAdd(&ksum[b * NTASK * DD + i0 + 2], acc.z);
    atomicAdd(&ksum[b * NTASK * DD + i0 + 3], acc.w);
  }
  if (tid == 0) {
    float c = 0.f;
    for (int s = 0; s < SCHUNK; ++s) c += valid[s];
    atomicAdd(&lensum[b], c);
  }
}

// ---------------------------------------------------------------------------
// Kernel 2a: query_enc[b,d] = dot(qsum[b,:], Wq[d,:]) / len[b] + bq[d]
// grid = BB*DD = 512 blocks, 256 threads, block-reduce.
// ---------------------------------------------------------------------------
__global__ void qenc_kernel(const float* __restrict__ qsum,
                            const float* __restrict__ lensum,
                            const float* __restrict__ Wq,
                            const float* __restrict__ bq,
                            float* __restrict__ qe)  // [BB*DD]
{
  int b = blockIdx.x >> 6;
  int d = blockIdx.x & 63;
  int tid = threadIdx.x;
  const float* wr = Wq + (size_t)d * HH;
  const float* qs = qsum + (size_t)b * HH;
  float acc = 0.f;
  for (int h = tid; h < HH; h += 256) acc += qs[h] * wr[h];
  __shared__ float red[256];
  red[tid] = acc;
  __syncthreads();
  for (int off = 128; off > 0; off >>= 1) {
    if (tid < off) red[tid] += red[tid + off];
    __syncthreads();
  }
  if (tid == 0) qe[blockIdx.x] = red[0] / lensum[b] + bq[d];
}

// ---------------------------------------------------------------------------
// Kernel 2b: key_enc + scores + softmax -> probs[BB,NTASK]. Single block.
// ---------------------------------------------------------------------------
__global__ void probs_kernel(const float* __restrict__ ksum,
                             const float* __restrict__ lensum,
                             const float* __restrict__ qe_g,
                             const float* __restrict__ Wk,
                             const float* __restrict__ bk,
                             float* __restrict__ probs)
{
  __shared__ float ke[BB * NTASK * DD];  // 16 KB
  __shared__ float qe[BB * DD];
  __shared__ float sc[BB * NTASK];
  int tid = threadIdx.x;
  for (int i = tid; i < BB * DD; i += 256) qe[i] = qe_g[i];
  for (int idx = tid; idx < BB * NTASK * DD; idx += 256) {
    int d = idx & 63;
    int bn = idx >> 6;
    int b = bn >> 3;
    const float* wr = Wk + d * DD;
    const float* ks = ksum + bn * DD;
    float acc = 0.f;
#pragma unroll 8
    for (int d2 = 0; d2 < DD; ++d2) acc += ks[d2] * wr[d2];
    ke[idx] = acc / lensum[b] + bk[d];
  }
  __syncthreads();
  if (tid < BB * NTASK) {
    int b = tid >> 3;
    float acc = 0.f;
    for (int d = 0; d < DD; ++d) acc += ke[tid * DD + d] * qe[b * DD + d];
    sc[tid] = acc / TEMP;
  }
  __syncthreads();
  if (tid < BB * NTASK) {
    int b = tid >> 3;
    float mx = -1e30f;
    for (int n = 0; n < NTASK; ++n) mx = fmaxf(mx, sc[b * NTASK + n]);
    float den = 0.f;
    for (int n = 0; n < NTASK; ++n) den += expf(sc[b * NTASK + n] - mx);
    probs[tid] = expf(sc[tid] - mx) / den;
  }
}

// ---------------------------------------------------------------------------
// Kernel 3: vmix[b,s,h] = sum_n probs[b,n] * value[b,s,n,h], cast to bf16.
// grid = BB*SS/VROWS = 2048 blocks, 256 threads; each block does 8 rows.
// Nontemporal value loads: 537 MB streaming, never reused -> don't evict
// vmix / B-panels from L2/L3. vmix stores stay cacheable (gemm re-reads).
// ---------------------------------------------------------------------------
#define VROWS 8
__global__ void vmix_kernel(const float* __restrict__ value,
                            const float* __restrict__ probs,
                            unsigned short* __restrict__ vmix)  // [BB*SS, HH] bf16
{
  __shared__ float p[NTASK];
  int bs0 = blockIdx.x * VROWS;
  int b = bs0 >> 11;  // SS = 2048
  if (threadIdx.x < NTASK) p[threadIdx.x] = probs[b * NTASK + threadIdx.x];
  __syncthreads();
  int h0 = threadIdx.x * 4;
  for (int r = 0; r < VROWS; ++r) {
    const float* vp = value + (size_t)(bs0 + r) * NTASK * HH;
    floatx4 acc = {0.f, 0.f, 0.f, 0.f};
#pragma unroll
    for (int n = 0; n < NTASK; ++n) {
      floatx4 v = __builtin_nontemporal_load(
          (const floatx4*)(vp + (size_t)n * HH + h0));
      acc += p[n] * v;
    }
    union { unsigned short us[4]; uint2 u2; } pk;
    pk.us[0] = f2bf(acc.x);
    pk.us[1] = f2bf(acc.y);
    pk.us[2] = f2bf(acc.z);
    pk.us[3] = f2bf(acc.w);
    *(uint2*)(vmix + (size_t)(bs0 + r) * HH + h0) = pk.u2;
  }
}

// ---------------------------------------------------------------------------
// Kernel 4: C[M=16384, N=1024] = A[M,K=1024](bf16) * B[N,K](bf16)^T + bv
// m97-style: global_load_lds width=16 staging into UNPADDED row-major LDS.
// 128x128 block tile, BK=32, 4 waves (each 64x64 = 4x4 MFMA 16x16x32 tiles).
// XCD-locality swizzle: 1D grid of 1024; the 8 column-blocks sharing one
// 256KB A-panel become temporally adjacent on the SAME XCD (round-robin
// linear%8 -> XCD). Per-XCD L2 then holds rotating A-panel + whole B (2MB).
// Bijective: 1024 % 8 == 0.
// ---------------------------------------------------------------------------
#define BM 128
#define BN 128
#define BK 32

#define GLDS16(gsrc, ldst)                                                     \
  __builtin_amdgcn_global_load_lds(                                           \
      (const __attribute__((address_space(1))) void*)(gsrc),                   \
      (__attribute__((address_space(3))) void*)(ldst), 16, 0, 0)

__global__ __launch_bounds__(256)
void gemm_kernel(const unsigned short* __restrict__ A,
                 const unsigned short* __restrict__ Bm,
                 const float* __restrict__ bv,
                 float* __restrict__ C)
{
  const int N = HH;  // 1024
  const int K = HH;  // 1024
  __shared__ unsigned short As[BM * BK];  // 8 KB, unpadded row-major
  __shared__ unsigned short Bs[BN * BK];  // 8 KB

  int tid = threadIdx.x;
  // XCD swizzle decode: b = xcd + 8*(ytile + 8*(xtile>>3)); xtile%8 == xcd
  int bflat = (int)blockIdx.x;
  int xcd = bflat & 7;
  int j = bflat >> 3;
  int ytile = j & 7;                  // column tile 0..7
  int xtile = xcd + ((j >> 3) << 3);  // row tile 0..127
  int m0 = xtile * BM;
  int n0 = ytile * BN;
  int wave = tid >> 6;
  int lane = tid & 63;
  int wr = wave >> 1, wc = wave & 1;
  int quad = lane >> 4;
  int l16 = lane & 15;

  floatx4 acc[4][4] = {};

  // Staging assignment: wave w covers rows [w*32, w*32+32) of both tiles,
  // via two 1KB global_load_lds per tile. Lane l -> row base+(l>>2), 16B
  // chunk (l&3). LDS dest = wave-uniform base + lane*16 (HW rule), which
  // equals row-major [row*BK + (l&3)*8] exactly (row stride = 64 B).
  int srow = wave * 32 + (lane >> 2);   // global row offset within tile
  int schk = (lane & 3) * 8;            // shorts
  const unsigned short* ga0 = A  + (size_t)(m0 + srow) * K + schk;
  const unsigned short* ga1 = ga0 + (size_t)16 * K;
  const unsigned short* gb0 = Bm + (size_t)(n0 + srow) * K + schk;
  const unsigned short* gb1 = gb0 + (size_t)16 * K;
  unsigned short* la0 = As + (wave * 32) * BK;
  unsigned short* la1 = As + (wave * 32 + 16) * BK;
  unsigned short* lb0 = Bs + (wave * 32) * BK;
  unsigned short* lb1 = Bs + (wave * 32 + 16) * BK;

  const int NKB = K / BK;  // 32
  for (int kb = 0; kb < NKB; ++kb) {
    int ko = kb * BK;
    GLDS16(ga0 + ko, la0);
    GLDS16(ga1 + ko, la1);
    GLDS16(gb0 + ko, lb0);
    GLDS16(gb1 + ko, lb1);
    __syncthreads();  // drains vmcnt: LDS tiles ready

    short8 af[4], bf[4];
#pragma unroll
    for (int mi = 0; mi < 4; ++mi)
      af[mi] = *(const short8*)&As[(wr * 64 + mi * 16 + l16) * BK + quad * 8];
#pragma unroll
    for (int ni = 0; ni < 4; ++ni)
      bf[ni] = *(const short8*)&Bs[(wc * 64 + ni * 16 + l16) * BK + quad * 8];
#pragma unroll
    for (int mi = 0; mi < 4; ++mi)
#pragma unroll
      for (int ni = 0; ni < 4; ++ni)
        acc[mi][ni] = __builtin_amdgcn_mfma_f32_16x16x32_bf16(
            af[mi], bf[ni], acc[mi][ni], 0, 0, 0);
    __syncthreads();  // all reads done; next iter may overwrite LDS
  }

  // epilogue: C/D layout col = lane&15, row = quad*4 + reg.
  // Nontemporal: C is never re-read -> don't pollute L2 (protect A/B panels).
#pragma unroll
  for (int ni = 0; ni < 4; ++ni) {
    int gn = n0 + wc * 64 + ni * 16 + l16;
    float bvv = bv[gn];
#pragma unroll
    for (int mi = 0; mi < 4; ++mi) {
      int gm = m0 + wr * 64 + mi * 16 + quad * 4;
#pragma unroll
      for (int r = 0; r < 4; ++r)
        __builtin_nontemporal_store(acc[mi][ni][r] + bvv,
                                    &C[(size_t)(gm + r) * N + gn]);
    }
  }
}

// ---------------------------------------------------------------------------
// Host launch
// ---------------------------------------------------------------------------
extern "C" void kernel_launch(void* const* d_in, const int* in_sizes, int n_in,
                              void* d_out, int out_size, void* d_ws, size_t ws_size,
                              hipStream_t stream) {
  const float* query = (const float*)d_in[0];
  const float* key   = (const float*)d_in[1];
  const float* value = (const float*)d_in[2];
  const int*   amask = (const int*)d_in[3];
  const float* Wq = (const float*)d_in[4];
  const float* bq = (const float*)d_in[5];
  const float* Wk = (const float*)d_in[6];
  const float* bk = (const float*)d_in[7];
  const float* Wv = (const float*)d_in[8];
  const float* bv = (const float*)d_in[9];
  float* out = (float*)d_out;

  char* ws = (char*)d_ws;
  // layout: vmix bf16 [16384*1024] (32 MB) | WvB bf16 [1024*1024] (2 MB) | small
  unsigned short* vmix = (unsigned short*)(ws);
  unsigned short* WvB  = (unsigned short*)(ws + (size_t)33554432);
  float* qsum   = (float*)(ws + (size_t)35651584);
  float* ksum   = qsum + BB * HH;          // 8192
  float* lensum = ksum + BB * NTASK * DD;  // +4096
  float* probs  = lensum + BB;             // +8
  float* qe     = probs + BB * NTASK;      // +64

  // zero the atomic accumulators (ws is poisoned 0xAA before every call)
  hipMemsetAsync(qsum, 0, (size_t)(BB * HH + BB * NTASK * DD + BB) * sizeof(float), stream);

  pool_kernel<<<BB * SCHUNKS, 256, 0, stream>>>(query, key, amask, Wv, qsum, ksum, lensum, WvB);
  qenc_kernel<<<BB * DD, 256, 0, stream>>>(qsum, lensum, Wq, bq, qe);
  probs_kernel<<<1, 256, 0, stream>>>(ksum, lensum, qe, Wk, bk, probs);
  vmix_kernel<<<BB * SS / VROWS, 256, 0, stream>>>(value, probs, vmix);
  gemm_kernel<<<1024, 256, 0, stream>>>(vmix, WvB, bv, out);
}

// Round 6
// 850.731 us; speedup vs baseline: 1.0265x; 1.0073x over previous
//
#include <hip/hip_runtime.h>
#include <hip/hip_bf16.h>
#include <stdint.h>

// Problem constants (reference: B,S,N,H,D = 8,2048,8,1024,64, T=50)
#define BB 8
#define SS 2048
#define NTASK 8
#define HH 1024
#define DD 64
#define TEMP 50.0f

typedef __attribute__((ext_vector_type(8))) short short8;   // 8 bf16 (4 VGPRs)
typedef __attribute__((ext_vector_type(4))) float floatx4;  // 4 fp32

static __device__ __forceinline__ unsigned short f2bf(float f) {
  // round-to-nearest-even fp32 -> bf16
  union { float f; unsigned int u; } v; v.f = f;
  unsigned int u = v.u;
  unsigned int r = u + 0x7FFFu + ((u >> 16) & 1u);
  return (unsigned short)(r >> 16);
}

// ---------------------------------------------------------------------------
// Kernel 1: masked pooling sums over S. grid = BB*64 blocks (64 s-chunks of 32),
// 256 threads. Accumulate via atomicAdd into zeroed ws buffers.
// valid[s] is BLOCK-UNIFORM -> `if (valid[s])` skips HBM fetch for masked rows.
// Also folds the Wv fp32->bf16 cast (512 blk * 256 thr * 8 = 1M elems).
// ---------------------------------------------------------------------------
#define SCHUNKS 64
#define SCHUNK (SS / SCHUNKS)  // 32

__global__ void pool_kernel(const float* __restrict__ query,
                            const float* __restrict__ key,
                            const int* __restrict__ amask,
                            const float* __restrict__ Wv,
                            float* __restrict__ qsum,    // [BB,HH]
                            float* __restrict__ ksum,    // [BB,NTASK*DD]
                            float* __restrict__ lensum,  // [BB]
                            unsigned short* __restrict__ WvB)
{
  __shared__ float valid[SCHUNK];
  int b = blockIdx.x >> 6;
  int chunk = blockIdx.x & 63;
  int s0 = chunk * SCHUNK;
  int tid = threadIdx.x;
  if (tid < SCHUNK) valid[tid] = (amask[b * SS + s0 + tid] == 0) ? 1.0f : 0.0f;
  __syncthreads();

  // Wv cast (independent of pooling): 8 consecutive elements per thread.
  {
    size_t i = ((size_t)blockIdx.x * 256 + tid) * 8;
    floatx4 v0 = *(const floatx4*)(Wv + i);
    floatx4 v1 = *(const floatx4*)(Wv + i + 4);
    union { unsigned short us[8]; uint4 u4; } pk;
    pk.us[0] = f2bf(v0.x); pk.us[1] = f2bf(v0.y);
    pk.us[2] = f2bf(v0.z); pk.us[3] = f2bf(v0.w);
    pk.us[4] = f2bf(v1.x); pk.us[5] = f2bf(v1.y);
    pk.us[6] = f2bf(v1.z); pk.us[7] = f2bf(v1.w);
    *(uint4*)(WvB + i) = pk.u4;
  }

  // query pooling: thread handles 4 consecutive h (float4), coalesced across lanes
  {
    const float* qb = query + ((size_t)b * SS + s0) * HH;
    int h0 = tid * 4;  // 256*4 = 1024 = HH
    floatx4 acc = {0.f, 0.f, 0.f, 0.f};
    for (int s = 0; s < SCHUNK; ++s) {
      if (valid[s] != 0.0f) {  // block-uniform branch: skip masked rows
        floatx4 v = *(const floatx4*)(qb + (size_t)s * HH + h0);
        acc += v;
      }
    }
    atomicAdd(&qsum[b * HH + h0 + 0], acc.x);
    atomicAdd(&qsum[b * HH + h0 + 1], acc.y);
    atomicAdd(&qsum[b * HH + h0 + 2], acc.z);
    atomicAdd(&qsum[b * HH + h0 + 3], acc.w);
  }
  // key pooling: NTASK*DD = 512 floats = 128 float4s; threads 0..127
  if (tid < 128) {
    const float* kb = key + ((size_t)b * SS + s0) * (NTASK * DD);
    int i0 = tid * 4;
    floatx4 acc = {0.f, 0.f, 0.f, 0.f};
    for (int s = 0; s < SCHUNK; ++s) {
      if (valid[s] != 0.0f) {
        floatx4 v = *(const floatx4*)(kb + (size_t)s * (NTASK * DD) + i0);
        acc += v;
      }
    }
    atomicAdd(&ksum[b * NTASK * DD + i0 + 0], acc.x);
    atomicAdd(&ksum[b * NTASK * DD + i0 + 1], acc.y);
    atomicAdd(&ksum[b * NTASK * DD + i0 + 2], acc.z);
    atomicAdd(&ksum[b * NTASK * DD + i0 + 3], acc.w);
  }
  if (tid == 0) {
    float c = 0.f;
    for (int s = 0; s < SCHUNK; ++s) c += valid[s];
    atomicAdd(&lensum[b], c);
  }
}

// ---------------------------------------------------------------------------
// Kernel 2a: query_enc[b,d] = dot(qsum[b,:], Wq[d,:]) / len[b] + bq[d]
// grid = BB*DD = 512 blocks, 256 threads, block-reduce.
// ---------------------------------------------------------------------------
__global__ void qenc_kernel(const float* __restrict__ qsum,
                            const float* __restrict__ lensum,
                            const float* __restrict__ Wq,
                            const float* __restrict__ bq,
                            float* __restrict__ qe)  // [BB*DD]
{
  int b = blockIdx.x >> 6;
  int d = blockIdx.x & 63;
  int tid = threadIdx.x;
  const float* wr = Wq + (size_t)d * HH;
  const float* qs = qsum + (size_t)b * HH;
  float acc = 0.f;
  for (int h = tid; h < HH; h += 256) acc += qs[h] * wr[h];
  __shared__ float red[256];
  red[tid] = acc;
  __syncthreads();
  for (int off = 128; off > 0; off >>= 1) {
    if (tid < off) red[tid] += red[tid + off];
    __syncthreads();
  }
  if (tid == 0) qe[blockIdx.x] = red[0] / lensum[b] + bq[d];
}

// ---------------------------------------------------------------------------
// Kernel 2b: key_enc + scores + softmax -> probs[BB,NTASK]. Single block.
// ---------------------------------------------------------------------------
__global__ void probs_kernel(const float* __restrict__ ksum,
                             const float* __restrict__ lensum,
                             const float* __restrict__ qe_g,
                             const float* __restrict__ Wk,
                             const float* __restrict__ bk,
                             float* __restrict__ probs)
{
  __shared__ float ke[BB * NTASK * DD];  // 16 KB
  __shared__ float qe[BB * DD];
  __shared__ float sc[BB * NTASK];
  int tid = threadIdx.x;
  for (int i = tid; i < BB * DD; i += 256) qe[i] = qe_g[i];
  for (int idx = tid; idx < BB * NTASK * DD; idx += 256) {
    int d = idx & 63;
    int bn = idx >> 6;
    int b = bn >> 3;
    const float* wr = Wk + d * DD;
    const float* ks = ksum + bn * DD;
    float acc = 0.f;
#pragma unroll 8
    for (int d2 = 0; d2 < DD; ++d2) acc += ks[d2] * wr[d2];
    ke[idx] = acc / lensum[b] + bk[d];
  }
  __syncthreads();
  if (tid < BB * NTASK) {
    int b = tid >> 3;
    float acc = 0.f;
    for (int d = 0; d < DD; ++d) acc += ke[tid * DD + d] * qe[b * DD + d];
    sc[tid] = acc / TEMP;
  }
  __syncthreads();
  if (tid < BB * NTASK) {
    int b = tid >> 3;
    float mx = -1e30f;
    for (int n = 0; n < NTASK; ++n) mx = fmaxf(mx, sc[b * NTASK + n]);
    float den = 0.f;
    for (int n = 0; n < NTASK; ++n) den += expf(sc[b * NTASK + n] - mx);
    probs[tid] = expf(sc[tid] - mx) / den;
  }
}

// ---------------------------------------------------------------------------
// Kernel 3 (FUSED vmix+gemm):
//   out[bs, o] = sum_h ( sum_n p[b,n]*value[bs,n,h] -> bf16 ) * WvB[o,h] + bv[o]
// grid = 256 blocks x 512 thr (8 waves). Block owns BM=64 rows x FULL N=1024
// (full-N => value read exactly ONCE, 537 MB, the HBM floor).
// Per K-step (BK=32):
//   A-tile (64x32 bf16, 4 KB): reg-staged from value (8 x floatx4 per thread,
//     nontemporal), mixed with p[] (bit-identical to old vmix), ds_write_b64.
//   B-tile (1024x32 bf16, 64 KB): global_load_lds x16B from L2-resident WvB.
// Double-buffered LDS (136 KB), ONE barrier per K-step; next-step loads are
// ISSUED BEFORE the MFMA cluster (T14 issue-early/write-late) so HBM latency
// hides under compute. Wave w computes rows[0..64) x cols[w*128,(w+1)*128):
// acc[4][8] of 16x16x32 MFMA. Frag/MFMA conventions identical to the
// previously-verified gemm (row-major [row][k] LDS, col=lane&15, row=quad*4+r).
// ---------------------------------------------------------------------------
#define BMF 64
#define BKF 32

#define GLDS16(gsrc, ldst)                                                     \
  __builtin_amdgcn_global_load_lds(                                           \
      (const __attribute__((address_space(1))) void*)(gsrc),                   \
      (__attribute__((address_space(3))) void*)(ldst), 16, 0, 0)

__global__ __launch_bounds__(512)
void fused_gemm_kernel(const float* __restrict__ value,      // [BB*SS, NTASK, HH]
                       const unsigned short* __restrict__ Bm, // WvB [HH, HH] bf16
                       const float* __restrict__ probs,       // [BB*NTASK]
                       const float* __restrict__ bv,          // [HH]
                       float* __restrict__ C)                 // [BB*SS, HH]
{
  __shared__ unsigned short As[2][BMF * BKF];  // 2 x 4 KB
  __shared__ unsigned short Bs[2][HH * BKF];   // 2 x 64 KB

  const int tid = threadIdx.x;
  const int wave = tid >> 6;
  const int lane = tid & 63;
  const int quad = lane >> 4;
  const int l16 = lane & 15;
  const int bs0 = (int)blockIdx.x * BMF;
  const int b = bs0 >> 11;  // SS = 2048, BMF divides SS

  // probs for this batch (block-uniform)
  float p[NTASK];
#pragma unroll
  for (int n = 0; n < NTASK; ++n) p[n] = probs[b * NTASK + n];

  // A-mix assignment: thread -> (row ar, 4-float k-chunk akq). 64*8 = 512. ✓
  const int ar = tid >> 3;         // 0..63
  const int akq = (tid & 7) * 4;   // 0,4,...,28
  const float* vrow = value + (size_t)(bs0 + ar) * (NTASK * HH) + akq;
  const int awr = ar * BKF + akq;  // LDS short offset; == linear tid*4 ✓

  // B staging: wave w stages rows [w*128, w*128+128) in 8 chunks of 16 rows.
  // GLDS dest = uniform base + lane*16B: lane l -> row +(l>>2), chunk (l&3)*8.
  const int brow = wave * 128 + (lane >> 2);
  const int bchk = (lane & 3) * 8;
  const unsigned short* gB = Bm + (size_t)brow * HH + bchk;

  floatx4 acc[4][8] = {};
  floatx4 v[NTASK];

  // ---- prologue: stage K-step 0 into buffer 0 ----
#pragma unroll
  for (int n = 0; n < NTASK; ++n)
    v[n] = __builtin_nontemporal_load((const floatx4*)(vrow + (size_t)n * HH));
#pragma unroll
  for (int c = 0; c < 8; ++c)
    GLDS16(gB + (size_t)(c * 16) * HH, &Bs[0][(wave * 128 + c * 16) * BKF]);
  {
    floatx4 m = {0.f, 0.f, 0.f, 0.f};
#pragma unroll
    for (int n = 0; n < NTASK; ++n) m += p[n] * v[n];
    union { unsigned short us[4]; uint2 u2; } pk;
    pk.us[0] = f2bf(m.x); pk.us[1] = f2bf(m.y);
    pk.us[2] = f2bf(m.z); pk.us[3] = f2bf(m.w);
    *(uint2*)&As[0][awr] = pk.u2;
  }
  __syncthreads();  // A(0), B(0) ready

  int cur = 0;
  for (int kb = 0; kb < 31; ++kb) {
    const int nxt = cur ^ 1;
    const int ko = (kb + 1) * BKF;

    // issue next-step loads BEFORE compute: HBM value -> regs, L2 B -> LDS[nxt]
#pragma unroll
    for (int n = 0; n < NTASK; ++n)
      v[n] = __builtin_nontemporal_load(
          (const floatx4*)(vrow + (size_t)n * HH + ko));
#pragma unroll
    for (int c = 0; c < 8; ++c)
      GLDS16(gB + (size_t)(c * 16) * HH + ko,
             &Bs[nxt][(wave * 128 + c * 16) * BKF]);

    // compute current K-step
    short8 af[4];
#pragma unroll
    for (int mi = 0; mi < 4; ++mi)
      af[mi] = *(const short8*)&As[cur][(mi * 16 + l16) * BKF + quad * 8];
#pragma unroll
    for (int ni = 0; ni < 8; ++ni) {
      short8 bf = *(const short8*)
          &Bs[cur][(wave * 128 + ni * 16 + l16) * BKF + quad * 8];
#pragma unroll
      for (int mi = 0; mi < 4; ++mi)
        acc[mi][ni] = __builtin_amdgcn_mfma_f32_16x16x32_bf16(
            af[mi], bf, acc[mi][ni], 0, 0, 0);
    }

    // finish next A-tile: mix the prefetched regs, write LDS[nxt]
    {
      floatx4 m = {0.f, 0.f, 0.f, 0.f};
#pragma unroll
      for (int n = 0; n < NTASK; ++n) m += p[n] * v[n];
      union { unsigned short us[4]; uint2 u2; } pk;
      pk.us[0] = f2bf(m.x); pk.us[1] = f2bf(m.y);
      pk.us[2] = f2bf(m.z); pk.us[3] = f2bf(m.w);
      *(uint2*)&As[nxt][awr] = pk.u2;
    }
    __syncthreads();  // drains GLDS16(nxt)+ds_writes; frag reads(cur) done
    cur = nxt;
  }

  // last K-step (kb=31): compute only
  {
    short8 af[4];
#pragma unroll
    for (int mi = 0; mi < 4; ++mi)
      af[mi] = *(const short8*)&As[cur][(mi * 16 + l16) * BKF + quad * 8];
#pragma unroll
    for (int ni = 0; ni < 8; ++ni) {
      short8 bf = *(const short8*)
          &Bs[cur][(wave * 128 + ni * 16 + l16) * BKF + quad * 8];
#pragma unroll
      for (int mi = 0; mi < 4; ++mi)
        acc[mi][ni] = __builtin_amdgcn_mfma_f32_16x16x32_bf16(
            af[mi], bf, acc[mi][ni], 0, 0, 0);
    }
  }

  // epilogue: C/D layout col = lane&15, row = quad*4 + reg. Nontemporal.
#pragma unroll
  for (int ni = 0; ni < 8; ++ni) {
    int gn = wave * 128 + ni * 16 + l16;
    float bvv = bv[gn];
#pragma unroll
    for (int mi = 0; mi < 4; ++mi) {
      int gm = bs0 + mi * 16 + quad * 4;
#pragma unroll
      for (int r = 0; r < 4; ++r)
        __builtin_nontemporal_store(acc[mi][ni][r] + bvv,
                                    &C[(size_t)(gm + r) * HH + gn]);
    }
  }
}

// ---------------------------------------------------------------------------
// Host launch
// ---------------------------------------------------------------------------
extern "C" void kernel_launch(void* const* d_in, const int* in_sizes, int n_in,
                              void* d_out, int out_size, void* d_ws, size_t ws_size,
                              hipStream_t stream) {
  const float* query = (const float*)d_in[0];
  const float* key   = (const float*)d_in[1];
  const float* value = (const float*)d_in[2];
  const int*   amask = (const int*)d_in[3];
  const float* Wq = (const float*)d_in[4];
  const float* bq = (const float*)d_in[5];
  const float* Wk = (const float*)d_in[6];
  const float* bk = (const float*)d_in[7];
  const float* Wv = (const float*)d_in[8];
  const float* bv = (const float*)d_in[9];
  float* out = (float*)d_out;

  char* ws = (char*)d_ws;
  // layout: WvB bf16 [1024*1024] (2 MB) | qsum | ksum | lensum | probs | qe
  unsigned short* WvB = (unsigned short*)(ws);
  float* qsum   = (float*)(ws + (size_t)2097152);
  float* ksum   = qsum + BB * HH;          // 8192
  float* lensum = ksum + BB * NTASK * DD;  // +4096
  float* probs  = lensum + BB;             // +8
  float* qe     = probs + BB * NTASK;      // +64

  // zero the atomic accumulators (ws is poisoned 0xAA before every call)
  hipMemsetAsync(qsum, 0, (size_t)(BB * HH + BB * NTASK * DD + BB) * sizeof(float), stream);

  pool_kernel<<<BB * SCHUNKS, 256, 0, stream>>>(query, key, amask, Wv, qsum, ksum, lensum, WvB);
  qenc_kernel<<<BB * DD, 256, 0, stream>>>(qsum, lensum, Wq, bq, qe);
  probs_kernel<<<1, 256, 0, stream>>>(ksum, lensum, qe, Wk, bk, probs);
  fused_gemm_kernel<<<BB * SS / BMF, 512, 0, stream>>>(value, WvB, probs, bv, out);
}